// Round 12
// baseline (334.904 us; speedup 1.0000x reference)
//
#include <hip/hip_runtime.h>
#include <math.h>

#define NB 32
#define GH 47
#define GW 47
#define NWIN (GH*GW)   // 2209
#define KSEL 16
#define RPITCH 17      // float4 per LDS row (68 floats)
#define SEG 48         // 8-wide horizontal segments per row

// ---------------------------------------------------------------------------
// Kernel A: per-window variance (verified separable f64 body) + fused
// per-batch top-16 tail. The 24th-arriving block of each batch (tracked via
// device-scope atomicAdd on cntA[b]) runs the verified r2/r6 LDS iterative
// argmax inline — no dedicated 32-block kernel, no extra launch gap, and
// per-batch top-k overlaps other batches' var work. No spin-waits.
// ---------------------------------------------------------------------------
__global__ __launch_bounds__(256) void k_var_sel(const float* __restrict__ x,
    float* __restrict__ var, int* __restrict__ cntA, int* __restrict__ coords)
{
    __shared__ double hs [3][24][SEG];
    __shared__ double hs2[3][24][SEG];
    __shared__ int   s_last;
    int gyp = blockIdx.x;     // 0..23
    int b   = blockIdx.y;
    int tid = threadIdx.x;
    int R0  = gyp * 16;

    for (int tau = tid; tau < 3*24*SEG; tau += 256) {
        int sg = tau % SEG;
        int t2 = tau / SEG;
        int rr = t2 % 24;
        int c  = t2 / 24;
        int row = R0 + rr;
        double s = 0.0, s2 = 0.0;
        if (row < 384) {
            const float* px = x + (((size_t)(b*3 + c)*384 + row)*384 + sg*8);
            #pragma unroll
            for (int q = 0; q < 2; ++q) {
                float4 v = *reinterpret_cast<const float4*>(px + q*4);
                double a0 = v.x, a1 = v.y, a2 = v.z, a3 = v.w;
                s  += a0 + a1 + a2 + a3;
                s2 = fma(a0,a0, fma(a1,a1, fma(a2,a2, fma(a3,a3, s2))));
            }
        }
        hs [c][rr][sg] = s;
        hs2[c][rr][sg] = s2;
    }
    __syncthreads();

    if (tid < 188) {
        int which = tid & 1;
        int rest  = tid >> 1;
        int gx = rest % 47, g = rest / 47;
        int gy = gyp*2 + g;
        if (gy < GH) {
            const double* base = which ? &hs2[0][0][0] : &hs[0][0][0];
            double S = 0.0;
            #pragma unroll
            for (int c = 0; c < 3; ++c)
                #pragma unroll
                for (int r = 0; r < 16; ++r) {
                    const double* rp = base + ((c*24) + (g*8 + r))*SEG + gx;
                    S += rp[0] + rp[1];
                }
            double P = __shfl_xor(S, 1, 64);
            if (which == 0) {
                var[(size_t)b*NWIN + gy*GW + gx] =
                    (float)((P - S*S/768.0) / 767.0);
            }
        }
    }

    // ---- completion count; 24th arriver runs this batch's top-16 ----
    __threadfence();
    if (tid == 0) s_last = (atomicAdd(&cntA[b], 1) == 23) ? 1 : 0;
    __syncthreads();
    if (!s_last) return;
    __threadfence();   // acquire: see other blocks' var writes

    // ---- r2/r6 top-16 (verified absmax 0): LDS iterative argmax ----
    float* lv = (float*)&hs[0][0][0];          // reuse 55 KB LDS (var reads done)
    __shared__ float s_val[4];
    __shared__ int   s_idx[4];
    __shared__ int   chosen[KSEL];
    int lane = tid & 63, wavid = tid >> 6;

    for (int i = tid; i < NWIN; i += 256) lv[i] = var[(size_t)b*NWIN + i];
    __syncthreads();

    for (int k = 0; k < KSEL; ++k) {
        float bv = -INFINITY; int bi = NWIN;
        for (int i = tid; i < NWIN; i += 256) {
            float v = lv[i];
            if (v > bv) { bv = v; bi = i; }
        }
        #pragma unroll
        for (int m = 1; m < 64; m <<= 1) {
            float ov = __shfl_xor(bv, m, 64);
            int   oi = __shfl_xor(bi, m, 64);
            if (ov > bv || (ov == bv && oi < bi)) { bv = ov; bi = oi; }
        }
        if (lane == 0) { s_val[wavid] = bv; s_idx[wavid] = bi; }
        __syncthreads();
        if (tid == 0) {
            float cv = s_val[0]; int ci = s_idx[0];
            #pragma unroll
            for (int wv = 1; wv < 4; ++wv) {
                if (s_val[wv] > cv || (s_val[wv] == cv && s_idx[wv] < ci)) {
                    cv = s_val[wv]; ci = s_idx[wv];
                }
            }
            chosen[k] = ci;
            lv[ci] = -INFINITY;
        }
        __syncthreads();
    }

    if (tid < KSEL) {
        int idx = chosen[tid];
        int h = (idx / 48) * 8; if (h > 320) h = 320;   // buggy /48 + clamp
        int w = (idx % 48) * 8; if (w > 320) w = 320;
        coords[(b*KSEL + tid)*2 + 0] = h;
        coords[(b*KSEL + tid)*2 + 1] = w;
    }
}

// ---------------------------------------------------------------------------
// Kernel B: conv1+ReLU + decimated partial sums (r11 verified body,
// block = (patch, row-group)) + fused per-batch reduce tail: the 32nd
// chunk-arriver per batch sums the 32 partial S[288] and does the
// out = b2 + w2*Ssum/4096 matvec inline.
// ---------------------------------------------------------------------------
__global__ __launch_bounds__(512, 2) void k_enc_red(const float* __restrict__ x,
    const float* __restrict__ w1, const float* __restrict__ b1,
    const float* __restrict__ w2, const float* __restrict__ b2,
    const int* __restrict__ coords, float* __restrict__ sbuf,
    int* __restrict__ cntB, float* __restrict__ out)
{
    __shared__ float4 sin4[3*33*RPITCH];    // [c][lr 0..32][17 f4], swizzled
    __shared__ float4 w1t4[27*8];           // [ch*9+ky*3+kx][8 quads of 4 oc]
    __shared__ float  s_part[8][2][4][3];   // [quad][iy-parity][i][kx]
    __shared__ float  s_c31[8][4][3];       // row-31 triple per quad (grp 1)
    __shared__ int    s_last;

    int bid  = blockIdx.x;
    int p    = bid >> 1;
    int grp  = bid & 1;
    int bimg = p >> 4;
    int tid  = threadIdx.x;
    int h0 = coords[p*2 + 0];
    int w0 = coords[p*2 + 1];

    float* sinf = (float*)sin4;
    float* w1tf = (float*)w1t4;

    for (int i = tid; i < 864; i += 512)
        w1tf[i] = w1[(i & 31)*27 + (i >> 5)];

    if (tid < 150) {
        if (tid < 99) {
            int c = tid / 33, lr = tid - c*33;
            int sw = (lr >> 1) & 7;
            sinf[((c*33 + lr)*RPITCH + sw)*4] = 0.f;
        } else if (grp == 0) {
            int j = tid - 99;                // 0..50
            int c = j / 17, f4i = j - c*17;
            sin4[(c*33 + 0)*RPITCH + f4i] = make_float4(0.f, 0.f, 0.f, 0.f);
        }
    }

    #pragma unroll
    for (int it = 0; it < 4; ++it) {
        int fi = tid + it*512;               // tasks < 1584
        if (fi < 3*33*16) {
            int c   = fi / 528;
            int rem = fi - c*528;
            int lr  = rem >> 4;              // 0..32
            int x4  = rem & 15;
            int y   = 32*grp + lr - 1;
            if (y >= 0) {
                float4 v = *reinterpret_cast<const float4*>(
                    x + (((size_t)(bimg*3 + c)*384 + (h0 + y))*384 + w0 + x4*4));
                int sw = (lr >> 1) & 7;
                float vals[4] = {v.x, v.y, v.z, v.w};
                #pragma unroll
                for (int e = 0; e < 4; ++e) {
                    int pcol = x4*4 + 1 + e;
                    int k  = pcol >> 2, bb = pcol & 3;
                    int ks = (k < 16) ? ((k & 8) | ((k & 7) ^ sw)) : 16;
                    sinf[((c*33 + lr)*RPITCH + ks)*4 + bb] = vals[e];
                }
            }
        }
    }
    __syncthreads();

    int wave = tid >> 6;
    int lane = tid & 63;
    int icq  = __builtin_amdgcn_readfirstlane(wave);  // ic-quad 0..7
    int iyl  = lane >> 2;              // local output row 0..15
    int xq   = lane & 3;               // 8-col quarter

    float acc[4][8];
    #pragma unroll
    for (int i = 0; i < 4; ++i)
        #pragma unroll
        for (int u = 0; u < 8; ++u) acc[i][u] = 0.f;

    #pragma unroll 1
    for (int ch = 0; ch < 3; ++ch) {
        #pragma unroll 1
        for (int ky = 0; ky < 3; ++ky) {
            int widx = ch*9 + ky*3;
            float4 wv0 = w1t4[(widx + 0)*8 + icq];
            float4 wv1 = w1t4[(widx + 1)*8 + icq];
            float4 wv2 = w1t4[(widx + 2)*8 + icq];
            const float* pw0 = (const float*)&wv0;
            const float* pw1 = (const float*)&wv1;
            const float* pw2 = (const float*)&wv2;

            int lr   = 2*iyl + ky;               // local padded row 0..32
            int sw   = (lr >> 1) & 7;
            int base = (ch*33 + lr)*RPITCH;
            float s[17];
            #pragma unroll
            for (int j = 0; j < 4; ++j) {
                int k = 4*xq + j;
                float4 v = sin4[base + ((k & 8) | ((k & 7) ^ sw))];
                s[4*j+0] = v.x; s[4*j+1] = v.y; s[4*j+2] = v.z; s[4*j+3] = v.w;
            }
            {
                int k  = 4*xq + 4;
                int ks = (k < 16) ? ((k & 8) | ((k & 7) ^ sw)) : 16;
                s[16] = sinf[(base + ks)*4];
            }
            #pragma unroll
            for (int i = 0; i < 4; ++i) {
                #pragma unroll
                for (int u = 0; u < 8; ++u)
                    acc[i][u] = fmaf(s[2*u], pw0[i],
                                 fmaf(s[2*u+1], pw1[i],
                                  fmaf(s[2*u+2], pw2[i], acc[i][u])));
            }
        }
    }

    float R[4][3];
    #pragma unroll
    for (int i = 0; i < 4; ++i) {
        float bias = b1[icq*4 + i];
        float c1 = 0.f, c2 = 0.f, v7 = 0.f;
        #pragma unroll
        for (int u = 0; u < 8; ++u) {
            float v = fmaxf(acc[i][u] + bias, 0.f);
            if (u & 1) c2 += v; else c1 += v;
            if (u == 7) v7 = v;
        }
        R[i][0] = c2 - ((xq == 3) ? v7 : 0.f);
        R[i][1] = c1;
        R[i][2] = c2;
    }

    #pragma unroll
    for (int m = 1; m <= 2; m <<= 1)
        #pragma unroll
        for (int i = 0; i < 4; ++i)
            #pragma unroll
            for (int k = 0; k < 3; ++k)
                R[i][k] += __shfl_xor(R[i][k], m, 64);

    float c31[4][3];
    #pragma unroll
    for (int i = 0; i < 4; ++i)
        #pragma unroll
        for (int k = 0; k < 3; ++k)
            c31[i][k] = __shfl(R[i][k], 60, 64);

    #pragma unroll
    for (int m = 8; m < 64; m <<= 1)
        #pragma unroll
        for (int i = 0; i < 4; ++i)
            #pragma unroll
            for (int k = 0; k < 3; ++k)
                R[i][k] += __shfl_xor(R[i][k], m, 64);

    if (lane == 0) {
        #pragma unroll
        for (int i = 0; i < 4; ++i)
            #pragma unroll
            for (int k = 0; k < 3; ++k)
                s_part[wave][0][i][k] = R[i][k];
    } else if (lane == 4) {
        #pragma unroll
        for (int i = 0; i < 4; ++i)
            #pragma unroll
            for (int k = 0; k < 3; ++k)
                s_part[wave][1][i][k] = R[i][k];
    } else if (lane == 8) {
        #pragma unroll
        for (int i = 0; i < 4; ++i)
            #pragma unroll
            for (int k = 0; k < 3; ++k)
                s_c31[wave][i][k] = c31[i][k];
    }
    __syncthreads();

    if (tid < 288) {
        int ic = tid / 9, j = tid - ic*9;
        int ky = j / 3, kx = j - ky*3;
        int q = ic >> 2, i = ic & 3;
        float even = s_part[q][0][i][kx];
        float odd  = s_part[q][1][i][kx];
        float val = (ky == 1) ? even : odd;
        if (ky == 0 && grp == 1) val = odd - s_c31[q][i][kx];
        sbuf[(size_t)bid*288 + tid] = val;
    }

    // ---- completion count; 32nd arriver runs this batch's reduce+matvec ----
    __threadfence();
    if (tid == 0) s_last = (atomicAdd(&cntB[bimg], 1) == 31) ? 1 : 0;
    __syncthreads();
    if (!s_last) return;
    __threadfence();   // acquire: see other chunks' sbuf writes

    float* Ssum  = sinf;         // reuse input-tile LDS (conv reads done)
    float* rpart = sinf + 288;

    for (int i = tid; i < 288; i += 512) {
        float s = 0.f;
        #pragma unroll
        for (int k = 0; k < 2*KSEL; ++k)
            s += sbuf[(size_t)(bimg*2*KSEL + k)*288 + i];
        Ssum[i] = s;
    }
    __syncthreads();

    if (tid < 256) {
        int oc = tid & 63, q = tid >> 6;
        const float4* w4 = reinterpret_cast<const float4*>(w2 + oc*288 + q*72);
        const float4* S4 = reinterpret_cast<const float4*>(Ssum + q*72);
        float a = 0.f;
        #pragma unroll
        for (int t = 0; t < 18; ++t) {
            float4 wv = w4[t];
            float4 sv = S4[t];
            a = fmaf(wv.x, sv.x, fmaf(wv.y, sv.y,
                 fmaf(wv.z, sv.z, fmaf(wv.w, sv.w, a))));
        }
        rpart[tid] = a;
    }
    __syncthreads();
    if (tid < 64) {
        float t = rpart[tid] + rpart[64 + tid] + rpart[128 + tid] + rpart[192 + tid];
        out[bimg*64 + tid] = b2[tid] + t * (1.0f/4096.0f);
    }
}

extern "C" void kernel_launch(void* const* d_in, const int* in_sizes, int n_in,
                              void* d_out, int out_size, void* d_ws, size_t ws_size,
                              hipStream_t stream)
{
    const float* x  = (const float*)d_in[0];
    const float* w1 = (const float*)d_in[1];
    const float* b1 = (const float*)d_in[2];
    const float* w2 = (const float*)d_in[3];
    const float* b2 = (const float*)d_in[4];
    float* out = (float*)d_out;

    char* ws = (char*)d_ws;
    int*   coords = (int*)ws;                        // 4,096 B
    float* var    = (float*)(ws + 4096);             // 282,752 B
    float* sbuf   = (float*)(ws + 287744);           // 1,179,648 B
    int*   cntA   = (int*)(ws + 1467392);            // 128 B
    int*   cntB   = (int*)(ws + 1467520);            // 128 B

    hipMemsetAsync(ws + 1467392, 0, 256, stream);    // zero both counters
    k_var_sel<<<dim3(24, NB), 256, 0, stream>>>(x, var, cntA, coords);
    k_enc_red<<<NB*KSEL*2,    512, 0, stream>>>(x, w1, b1, w2, b2,
                                                coords, sbuf, cntB, out);
}